// Round 4
// baseline (1035.084 us; speedup 1.0000x reference)
//
#include <hip/hip_runtime.h>
#include <math.h>

#define NCLS 9

typedef __attribute__((ext_vector_type(8))) short short8;
typedef __attribute__((ext_vector_type(4))) float f32x4;

__device__ __forceinline__ unsigned short f2bf(float f) {
    unsigned int u = __float_as_uint(f);
    return (unsigned short)((u + 0x7fffu + ((u >> 16) & 1u)) >> 16);  // RNE
}

__device__ __forceinline__ short8 as_s8(uint4 v) {
    union { uint4 u; short8 s; } x; x.u = v; return x.s;
}

__device__ __forceinline__ float fast_tanh(float x) {
    // tanh(x) = 1 - 2/(2^(x*2*log2e) + 1); saturates correctly at +/-1
    float s = x * 2.885390081777927f;
    float e, r;
    asm("v_exp_f32 %0, %1" : "=v"(e) : "v"(s));
    asm("v_rcp_f32 %0, %1" : "=v"(r) : "v"(e + 1.0f));
    return fmaf(-2.0f, r, 1.0f);
}

// Fused 2-layer persistent MFMA RNN. 32 blocks x 16 batch rows, 256 threads
// (4 waves). Wave w owns 64 output cols as 4 B-tiles in registers.
// h LDS layout is A-read-native: 16B cell (kk,g2,row) holds h[row] bf16 for
// k = kk*32+g2*8 .. +8, cell index swizzled by XOR(cidx&7) so that
//  - A-read (per kk): 64 contiguous cells = 1KB, zero bank conflicts
//  - h-write: one b64 per row, ~2-way max.
// Phase 0: T=1024 over x; final h1 -> seq2[col][row] (fp32, LDS).
// Phase 1: T=256 over seq2; final h2 -> global.
__global__ __launch_bounds__(256, 1) void rnn_fused_kernel(
    const float* __restrict__ x,     // [B, 1024]
    const float* __restrict__ W1, const float* __restrict__ U1, const float* __restrict__ b1,
    const float* __restrict__ W2, const float* __restrict__ U2, const float* __restrict__ b2,
    float* __restrict__ h2out)       // [B, 256]
{
    const int tid  = threadIdx.x;
    const int w    = tid >> 6;
    const int lane = tid & 63;
    const int g    = lane >> 4;
    const int l16  = lane & 15;
    const int b0   = blockIdx.x << 4;

    __shared__ unsigned char h_lds[2][8192];   // 512 cells x 16B, swizzled
    __shared__ float xchunk[128][16];          // phase-0 seq prefetch [t][row]
    __shared__ float seq2[256][16];            // phase-1 sequence = h1 [col][row]

    // h-write addressing: cols c = w*64 + l16*4 + t4 -> kk = w*2+(l16>>3),
    // g2 = (l16>>1)&3, e0 = 4*(l16&1); cidx = kk*4+g2.
    const int cidx  = w * 8 + ((l16 >> 3) << 2) + ((l16 >> 1) & 3);
    const int phi   = cidx & 7;
    const int wbase = cidx * 256 + ((l16 & 1) << 3);
    const int crow  = g * 4;

#pragma unroll 1
    for (int p = 0; p < 2; ++p) {
        const float* W    = p ? W2 : W1;
        const float* U    = p ? U2 : U1;
        const float* bias = p ? b2 : b1;
        const int    T    = p ? 256 : 1024;

        // ---- B-fragments for this layer's U (bf16, registers) ----
        uint4 bfrag[4][8];
        {
            const int colbase = w * 64 + l16 * 4;
            #pragma unroll
            for (int t4 = 0; t4 < 4; ++t4) {
                #pragma unroll
                for (int kk = 0; kk < 8; ++kk) {
                    unsigned int d[4];
                    #pragma unroll
                    for (int pr = 0; pr < 4; ++pr) {
                        const int k0 = kk * 32 + g * 8 + 2 * pr;
                        d[pr] = (unsigned)f2bf(U[k0 * 256 + colbase + t4])
                              | ((unsigned)f2bf(U[(k0 + 1) * 256 + colbase + t4]) << 16);
                    }
                    bfrag[t4][kk] = make_uint4(d[0], d[1], d[2], d[3]);
                }
            }
        }
        #pragma unroll
        for (int t4 = 0; t4 < 4; ++t4)
            #pragma unroll
            for (int kk = 0; kk < 8; ++kk)
                asm volatile("" : "+v"(bfrag[t4][kk].x), "+v"(bfrag[t4][kk].y),
                                  "+v"(bfrag[t4][kk].z), "+v"(bfrag[t4][kk].w));

        const float4 wv = *(const float4*)&W[w * 64 + l16 * 4];
        const float4 bv = *(const float4*)&bias[w * 64 + l16 * 4];
        const float wvr[4] = {wv.x, wv.y, wv.z, wv.w};
        const float bvr[4] = {bv.x, bv.y, bv.z, bv.w};

        // zero h buffer 0
        for (int idx = tid; idx < 2048; idx += 256)
            ((unsigned int*)h_lds[0])[idx] = 0u;
        __syncthreads();

        for (int t = 0; t < T; ++t) {
            if (p == 0 && (t & 127) == 0) {
                // coalesced prefetch: 16 rows x 128 t
                for (int idx = tid; idx < 2048; idx += 256) {
                    const int row = idx >> 7, dt = idx & 127;
                    xchunk[dt][row] = x[(b0 + row) * 1024 + t + dt];
                }
                __syncthreads();
            }
            const int cur = t & 1;
            const int nxt = cur ^ 1;

            // A-fragments: contiguous 1KB per kk, conflict-free
            uint4 a[8];
            #pragma unroll
            for (int kk = 0; kk < 8; ++kk) {
                const int cell = kk * 64 + g * 16 + l16;
                a[kk] = *(const uint4*)&h_lds[cur][(cell ^ ((kk * 4 + g) & 7)) << 4];
            }

            f32x4 accA[4], accB[4];
            #pragma unroll
            for (int t4 = 0; t4 < 4; ++t4) {
                accA[t4] = (f32x4){0.f, 0.f, 0.f, 0.f};
                accB[t4] = (f32x4){0.f, 0.f, 0.f, 0.f};
            }
            // two 4-deep chains per tile (even/odd kk)
            #pragma unroll
            for (int kp = 0; kp < 4; ++kp) {
                #pragma unroll
                for (int t4 = 0; t4 < 4; ++t4) {
                    accA[t4] = __builtin_amdgcn_mfma_f32_16x16x32_bf16(
                        as_s8(a[2 * kp]), as_s8(bfrag[t4][2 * kp]), accA[t4], 0, 0, 0);
                    accB[t4] = __builtin_amdgcn_mfma_f32_16x16x32_bf16(
                        as_s8(a[2 * kp + 1]), as_s8(bfrag[t4][2 * kp + 1]), accB[t4], 0, 0, 0);
                }
            }

            const float4 sv = p ? *(const float4*)&seq2[t][crow]
                                : *(const float4*)&xchunk[t & 127][crow];
            const float svr[4] = {sv.x, sv.y, sv.z, sv.w};

            #pragma unroll
            for (int r = 0; r < 4; ++r) {
                float hf[4];
                #pragma unroll
                for (int t4 = 0; t4 < 4; ++t4) {
                    const float v = (accA[t4][r] + accB[t4][r])
                                  + fmaf(svr[r], wvr[t4], bvr[t4]);
                    hf[t4] = fast_tanh(v);
                }
                unsigned lo, hi;
                asm("v_cvt_pk_bf16_f32 %0, %1, %2" : "=v"(lo) : "v"(hf[0]), "v"(hf[1]));
                asm("v_cvt_pk_bf16_f32 %0, %1, %2" : "=v"(hi) : "v"(hf[2]), "v"(hf[3]));
                const int rowx = (crow + r) ^ phi;
                *(uint2*)&h_lds[nxt][wbase + (rowx << 4)] = make_uint2(lo, hi);

                if (t == T - 1) {
                    const int colb = w * 64 + l16 * 4;
                    if (p == 0) {
                        #pragma unroll
                        for (int t4 = 0; t4 < 4; ++t4)
                            seq2[colb + t4][crow + r] = hf[t4];
                    } else {
                        *(float4*)&h2out[(b0 + crow + r) * 256 + colb] =
                            make_float4(hf[0], hf[1], hf[2], hf[3]);
                    }
                }
            }
            __syncthreads();
        }
    }
}

// Tiny MLP head: one block per batch row, 128 threads.
__global__ __launch_bounds__(128) void mlp_kernel(
    const float* __restrict__ h2,
    const float* __restrict__ Wd1, const float* __restrict__ bd1,
    const float* __restrict__ Wd2, const float* __restrict__ bd2,
    const float* __restrict__ Wd3, const float* __restrict__ bd3,
    const float* __restrict__ Wd4, const float* __restrict__ bd4,
    float* __restrict__ out)
{
    const int b   = blockIdx.x;
    const int tid = threadIdx.x;

    __shared__ float hin[256];
    __shared__ float z1[128];
    __shared__ float z2[64];
    __shared__ float z3[32];

    hin[tid]       = h2[b * 256 + tid];
    hin[tid + 128] = h2[b * 256 + tid + 128];
    __syncthreads();

    {
        float a = bd1[tid];
#pragma unroll 8
        for (int i = 0; i < 256; ++i) a += hin[i] * Wd1[i * 128 + tid];
        z1[tid] = fmaxf(a, 0.0f);
    }
    __syncthreads();
    if (tid < 64) {
        float a = bd2[tid];
#pragma unroll 8
        for (int i = 0; i < 128; ++i) a += z1[i] * Wd2[i * 64 + tid];
        z2[tid] = fmaxf(a, 0.0f);
    }
    __syncthreads();
    if (tid < 32) {
        float a = bd3[tid];
#pragma unroll 8
        for (int i = 0; i < 64; ++i) a += z2[i] * Wd3[i * 32 + tid];
        z3[tid] = fmaxf(a, 0.0f);
    }
    __syncthreads();
    if (tid < NCLS) {
        float a = bd4[tid];
#pragma unroll
        for (int i = 0; i < 32; ++i) a += z3[i] * Wd4[i * NCLS + tid];
        out[b * NCLS + tid] = a;
    }
}

extern "C" void kernel_launch(void* const* d_in, const int* in_sizes, int n_in,
                              void* d_out, int out_size, void* d_ws, size_t ws_size,
                              hipStream_t stream) {
    const float* x   = (const float*)d_in[0];
    const float* W1  = (const float*)d_in[1];
    const float* U1  = (const float*)d_in[2];
    const float* b1  = (const float*)d_in[3];
    const float* W2  = (const float*)d_in[4];
    const float* U2  = (const float*)d_in[5];
    const float* b2  = (const float*)d_in[6];
    const float* Wd1 = (const float*)d_in[7];
    const float* bd1 = (const float*)d_in[8];
    const float* Wd2 = (const float*)d_in[9];
    const float* bd2 = (const float*)d_in[10];
    const float* Wd3 = (const float*)d_in[11];
    const float* bd3 = (const float*)d_in[12];
    const float* Wd4 = (const float*)d_in[13];
    const float* bd4 = (const float*)d_in[14];

    float* out = (float*)d_out;
    float* h2  = (float*)d_ws;        // 512*256 fp32

    rnn_fused_kernel<<<32, 256, 0, stream>>>(x, W1, U1, b1, W2, U2, b2, h2);
    mlp_kernel<<<512, 128, 0, stream>>>(h2, Wd1, bd1, Wd2, bd2, Wd3, bd3, Wd4, bd4, out);
}